// Round 11
// baseline (168.510 us; speedup 1.0000x reference)
//
#include <hip/hip_runtime.h>
#include <hip/hip_bf16.h>
#include <math.h>

// Problem constants (reference: B=8, H=W=512)
#define Bsz    8
#define Wdim   512
#define HWv    (512 * 512)       // 262144 = 2^18
#define LOG2HW 18
#define NIMG   16                // {bg(0..7), fg(8..15)}
#define TILE   64                // 64x64 tiles -> 8x8 = 64 tiles per image
#define TPIX   (TILE * TILE)     // 4096
#define RCAP   2048              // max roots per tile per mask (<= runs <= 2048)

// ws layout (bytes, all 8-aligned):
//   parent   int[16*HW]    16.78 MB  (sparse: only root slots touched)
//   areas    int[16*HW]    16.78 MB  (sparse: only root slots touched)
//   L16      u16[16*HW]     8.39 MB  (per-pixel in-tile local root or 0xFFFF)
//   rootPack u32[16*64*2048] 8.39 MB (local<<13 | area)
//   rootF    int[16*64*2048] 8.39 MB (final root, then total area)
//   rootCnt  int[16*64]
//   bL/bR/bT/bB int[16*64*64] each   (border-col/row global root ids or -1)
//   maxa[16]; double sums[2]; int counts[2]
// total ~60 MB (ws is 256 MiB per the harness fill).

// ---------------- union-find (atomicMin only: parents monotone decreasing,
// links point to smaller index => lock-free correct). ----------------
__device__ __forceinline__ int uf_find(int* L, int x) {
  int p = L[x];
  while (p != x) {
    int gp = L[p];
    if (gp != p) atomicMin(&L[x], gp);
    x = gp;
    p = L[x];
  }
  return x;
}

__device__ __forceinline__ int find_ro(const int* __restrict__ L, int x) {
  int p = L[x];
  while (p != x) { x = p; p = L[x]; }
  return x;
}

__device__ __forceinline__ void uf_union(int* L, int a, int b) {
  a = uf_find(L, a);
  b = uf_find(L, b);
  while (a != b) {
    if (a < b) { int t = a; a = b; b = t; }
    int old = atomicMin(&L[a], b);
    if (old == a) return;
    a = old;
  }
}

// ---------------- kernels ----------------

// One block per (batch, tile): BOTH masks. LDS run-based CCL; outputs:
// u16 local-root labels, packed root list, sparse parent/areas init,
// border root arrays. No full-image int32 label/area writes.
__global__ __launch_bounds__(1024) void k_local(const float* __restrict__ cams,
    int* __restrict__ parent, int* __restrict__ areas,
    unsigned short* __restrict__ L16, unsigned int* __restrict__ rootPack,
    int* __restrict__ rootCnt, int* __restrict__ bL, int* __restrict__ bR,
    int* __restrict__ bT, int* __restrict__ bB) {
  int b    = blockIdx.x >> 6;          // 0..7
  int tile = blockIdx.x & 63;
  int oy = (tile >> 3) * TILE, ox = (tile & 7) * TILE;
  int tid = threadIdx.x, lane = tid & 63;

  __shared__ int P[2][TPIX];           // 32 KB
  __shared__ int A[2][TPIX];           // 32 KB
  __shared__ int rc[2];
  if (tid < 2) rc[tid] = 0;

  // P1: one cam read, both masks' run-start init (wave == one row)
  #pragma unroll
  for (int it = 0; it < 4; ++it) {
    int i  = it * 1024 + tid;          // i & 63 == lane
    int ly = i >> 6;
    float c = cams[(b << LOG2HW) + ((oy + ly) << 9) + ox + lane];
    #pragma unroll
    for (int m = 0; m < 2; ++m) {
      bool msk = m ? (c > 0.6f) : (c >= 0.2f);
      unsigned long long bm = __ballot(msk);
      int par = -1;
      if (msk) {
        unsigned long long below = (1ULL << lane) - 1ULL;
        unsigned long long z = (~bm) & below;
        int rs = z ? (64 - __clzll(z)) : 0;
        par = (ly << 6) + rs;
      }
      P[m][i] = par;
      A[m][i] = 0;
    }
  }
  __syncthreads();

  // P2: vertical unions, one per overlap segment (dedup via west pair)
  #pragma unroll
  for (int it = 0; it < 4; ++it) {
    int i = it * 1024 + tid;
    if (i >= TILE) {
      #pragma unroll
      for (int m = 0; m < 2; ++m) {
        if (P[m][i] >= 0 && P[m][i - TILE] >= 0) {
          bool skip = (lane > 0) && (P[m][i - 1] >= 0) && (P[m][i - TILE - 1] >= 0);
          if (!skip) uf_union(P[m], i, i - TILE);
        }
      }
    }
  }
  __syncthreads();

  // P3: per-run find + shuffle broadcast + per-run area add
  #pragma unroll
  for (int it = 0; it < 4; ++it) {
    int i = it * 1024 + tid;
    #pragma unroll
    for (int m = 0; m < 2; ++m) {
      bool msk = P[m][i] >= 0;
      unsigned long long bm = __ballot(msk);
      int rs = 0;
      if (msk) {
        unsigned long long below = (1ULL << lane) - 1ULL;
        unsigned long long z = (~bm) & below;
        rs = z ? (64 - __clzll(z)) : 0;
      }
      bool isStart = msk && (rs == lane);
      int r = -1;
      if (isStart) r = find_ro(P[m], i);
      int root = __shfl(r, rs);
      if (msk) P[m][i] = root;
      if (isStart) {
        unsigned long long t = (~bm) >> lane;
        int runlen = t ? (__ffsll((long long)t) - 1) : (64 - lane);
        atomicAdd(&A[m][root], runlen);
      }
    }
  }
  __syncthreads();

  // P4: write L16; roots -> list entry + sparse parent/areas init
  #pragma unroll
  for (int it = 0; it < 4; ++it) {
    int i  = it * 1024 + tid;
    int ly = i >> 6, lx = i & 63;
    int g  = ((oy + ly) << 9) + ox + lx;
    #pragma unroll
    for (int m = 0; m < 2; ++m) {
      int imgm = m * 8 + b;
      int p = P[m][i];
      L16[((size_t)imgm << LOG2HW) + g] = (p < 0) ? (unsigned short)0xFFFF
                                                  : (unsigned short)p;
      if (p == i) {                    // tile root (g == gpix(i))
        int slot = atomicAdd(&rc[m], 1);
        parent[(imgm << LOG2HW) + g] = g;
        areas [(imgm << LOG2HW) + g] = 0;
        rootPack[(((imgm << 6) + tile) * RCAP) + slot] =
            ((unsigned)i << 13) | (unsigned)A[m][i];
      }
    }
  }
  __syncthreads();
  if (tid < 2) rootCnt[(((tid * 8 + b) << 6) + tile)] = rc[tid];
  // border publish: 2 masks x 4 edges x 64 = 512 items
  if (tid < 512) {
    int m = tid >> 8, rem = tid & 255, e = rem >> 6, k = rem & 63;
    int i = (e == 0) ? (k << 6) : (e == 1) ? ((k << 6) + 63)
          : (e == 2) ? k : ((63 << 6) + k);
    int p = P[m][i];
    int val = (p < 0) ? -1 : (((oy + (p >> 6)) << 9) + ox + (p & 63));
    int idx = (((m * 8 + b) << 6) + tile) * 64 + k;
    if (e == 0) bL[idx] = val; else if (e == 1) bR[idx] = val;
    else if (e == 2) bT[idx] = val; else bB[idx] = val;
  }
}

// Border unions straight from the published root arrays (no label reads).
// Grid exactly 16*7168/256 = 448 blocks. Block 0 also inits maxa/sums/counts.
__global__ void k_border(int* __restrict__ parent, const int* __restrict__ bL,
                         const int* __restrict__ bR, const int* __restrict__ bT,
                         const int* __restrict__ bB, int* __restrict__ maxa,
                         double* __restrict__ sums, int* __restrict__ counts) {
  if (blockIdx.x == 0) {
    if (threadIdx.x < NIMG) maxa[threadIdx.x] = 0;
    if (threadIdx.x < 2) { sums[threadIdx.x] = 0.0; counts[threadIdx.x] = 0; }
  }
  int t = blockIdx.x * blockDim.x + threadIdx.x;
  int img = t / 7168;
  int r   = t - img * 7168;
  int* Lp = parent + (img << LOG2HW);
  if (r < 3584) {                       // vertical boundaries: 7 cols x 8 rows
    int v = r >> 6, y = r & 63;
    int tXl = v >> 3, tYv = v & 7;      // tXl 0..6, tYv 0..7
    int tileL = tYv * 8 + tXl;
    int baseR = ((img << 6) + tileL) * 64;
    int baseL = ((img << 6) + tileL + 1) * 64;
    int pr = bR[baseR + y], qr = bL[baseL + y];
    if (pr >= 0 && qr >= 0) {
      bool skip = (y > 0) && (bR[baseR + y - 1] >= 0) && (bL[baseL + y - 1] >= 0);
      if (!skip) uf_union(Lp, pr, qr);
    }
  } else {                              // horizontal boundaries: 7 rows x 8 cols
    int r2 = r - 3584;
    int h = r2 >> 6, x = r2 & 63;
    int tYt = h >> 3, tX = h & 7;       // tYt 0..6
    int tileT = tYt * 8 + tX;
    int baseB = ((img << 6) + tileT) * 64;
    int baseT = ((img << 6) + tileT + 8) * 64;
    int pr = bB[baseB + x], qr = bT[baseT + x];
    if (pr >= 0 && qr >= 0) {
      bool skip = (x > 0) && (bB[baseB + x - 1] >= 0) && (bT[baseT + x - 1] >= 0);
      if (!skip) uf_union(Lp, pr, qr);
    }
  }
}

// Root-list flatten: find final root, push area (non-returning), record f.
__global__ void k_flatten(int* __restrict__ parent, int* __restrict__ areas,
                          const unsigned int* __restrict__ rootPack,
                          int* __restrict__ rootF, const int* __restrict__ rootCnt) {
  int lt = blockIdx.x;                  // imgm*64 + tile
  int imgm = lt >> 6, tile = lt & 63;
  int oy = (tile >> 3) * TILE, ox = (tile & 7) * TILE;
  int cnt = rootCnt[lt];
  const int* Lp = parent + (imgm << LOG2HW);
  for (int k = threadIdx.x; k < cnt; k += blockDim.x) {
    unsigned pk = rootPack[lt * RCAP + k];
    int loc = pk >> 13, area = pk & 8191;
    int gr = ((oy + (loc >> 6)) << 9) + ox + (loc & 63);
    int f = find_ro(Lp, gr);
    atomicAdd(&areas[(imgm << LOG2HW) + f], area);
    rootF[lt * RCAP + k] = f;
  }
}

// Root-list max: gather totals, cache them into rootF, 1 atomicMax/block.
__global__ void k_max(const int* __restrict__ areas, int* __restrict__ rootF,
                      const int* __restrict__ rootCnt, int* __restrict__ maxa) {
  int lt = blockIdx.x;
  int imgm = lt >> 6;
  int cnt = rootCnt[lt];
  int m = 0;
  for (int k = threadIdx.x; k < cnt; k += blockDim.x) {
    int tot = areas[(imgm << LOG2HW) + rootF[lt * RCAP + k]];
    rootF[lt * RCAP + k] = tot;         // cache total for k_keepce
    m = max(m, tot);
  }
  #pragma unroll
  for (int off = 32; off > 0; off >>= 1)
    m = max(m, __shfl_down(m, off));
  __shared__ int lm[4];
  int wave = threadIdx.x >> 6;
  if ((threadIdx.x & 63) == 0) lm[wave] = m;
  __syncthreads();
  if (threadIdx.x == 0) {
    int bm = max(max(lm[0], lm[1]), max(lm[2], lm[3]));
    if (bm > 0) atomicMax(&maxa[imgm], bm);
  }
}

// Verdict table from root lists (zero area gathers: totals cached in rootF);
// pixels via u16 local labels; preds float4 stream; block reduce + 4 atomics.
__global__ __launch_bounds__(1024) void k_keepce(const float* __restrict__ preds,
    const unsigned short* __restrict__ L16, const unsigned int* __restrict__ rootPack,
    const int* __restrict__ rootF, const int* __restrict__ rootCnt,
    const int* __restrict__ maxa, double* __restrict__ sums, int* __restrict__ counts) {
  int b = blockIdx.x >> 6, tile = blockIdx.x & 63;
  int oy = (tile >> 3) * TILE, ox = (tile & 7) * TILE;
  __shared__ unsigned short V[2][TPIX];  // 16 KB (only root slots referenced)
  int mx0 = maxa[b], mx1 = maxa[8 + b];
  #pragma unroll
  for (int m = 0; m < 2; ++m) {
    int lt = (((m * 8 + b) << 6) + tile);
    int cnt = rootCnt[lt];
    int mxm = m ? mx1 : mx0;
    for (int k = threadIdx.x; k < cnt; k += 1024) {
      unsigned pk = rootPack[lt * RCAP + k];
      int tot = rootF[lt * RCAP + k];
      V[m][pk >> 13] = (2 * tot > mxm) ? 1 : 0;
    }
  }
  __syncthreads();

  int i0 = threadIdx.x << 2;            // 4 px per thread
  int ly = i0 >> 6, lx = i0 & 63;
  int g  = ((oy + ly) << 9) + ox + lx;
  ushort4 ub4 = *(const ushort4*)&L16[((size_t)b << LOG2HW) + g];
  ushort4 uf4 = *(const ushort4*)&L16[((size_t)(8 + b) << LOG2HW) + g];
  float4 A0[3], A1[3];
  #pragma unroll
  for (int p = 0; p < 3; p++) {
    const float* pb = preds + ((size_t)((p * Bsz + b) * 2) << LOG2HW);
    A0[p] = *(const float4*)&pb[g];
    A1[p] = *(const float4*)&pb[HWv + g];
  }
  unsigned short lb[4] = {ub4.x, ub4.y, ub4.z, ub4.w};
  unsigned short lf[4] = {uf4.x, uf4.y, uf4.z, uf4.w};
  bool vf[4], vb[4];
  #pragma unroll
  for (int j = 0; j < 4; j++) {
    bool kb = (lb[j] != 0xFFFF) && (V[0][lb[j] & 4095] != 0);
    bool kf = (lf[j] != 0xFFFF) && (V[1][lf[j] & 4095] != 0);
    vb[j] = !kb;                        // bg valid where NOT kept
    vf[j] = kf;                         // fg valid where kept
  }
  int cf = (int)vf[0] + vf[1] + vf[2] + vf[3];
  int cb = (int)vb[0] + vb[1] + vb[2] + vb[3];
  float sfg = 0.f, sbg = 0.f;
  #pragma unroll
  for (int p = 0; p < 3; p++) {
    float d[4] = {A0[p].x - A1[p].x, A0[p].y - A1[p].y,
                  A0[p].z - A1[p].z, A0[p].w - A1[p].w};
    #pragma unroll
    for (int j = 0; j < 4; j++) {
      float sp = logf(1.f + expf(-fabsf(d[j])));
      sfg += vf[j] ? (fmaxf(d[j], 0.f) + sp) : 0.f;
      sbg += vb[j] ? (fmaxf(-d[j], 0.f) + sp) : 0.f;
    }
  }
  #pragma unroll
  for (int off = 32; off > 0; off >>= 1) {
    sfg += __shfl_down(sfg, off);
    sbg += __shfl_down(sbg, off);
    cf  += __shfl_down(cf, off);
    cb  += __shfl_down(cb, off);
  }
  __shared__ float lsf[16], lsb[16];
  __shared__ int   lcf[16], lcb[16];
  int wave = threadIdx.x >> 6;
  if ((threadIdx.x & 63) == 0) {
    lsf[wave] = sfg; lsb[wave] = sbg; lcf[wave] = cf; lcb[wave] = cb;
  }
  __syncthreads();
  if (threadIdx.x == 0) {
    float tf = 0.f, tb = 0.f; int af_ = 0, ab_ = 0;
    #pragma unroll
    for (int w = 0; w < 16; w++) { tf += lsf[w]; tb += lsb[w]; af_ += lcf[w]; ab_ += lcb[w]; }
    atomicAdd(&sums[0], (double)tf);
    atomicAdd(&sums[1], (double)tb);
    atomicAdd(&counts[0], af_);
    atomicAdd(&counts[1], ab_);
  }
}

__global__ void k_final(const double* __restrict__ sums, const int* __restrict__ counts,
                        float* __restrict__ out) {
  if (threadIdx.x == 0 && blockIdx.x == 0) {
    double df = counts[0] > 0 ? (double)counts[0] : 1.0;
    double db = counts[1] > 0 ? (double)counts[1] : 1.0;
    out[0] = (float)(sums[0] / df + sums[1] / db);
  }
}

extern "C" void kernel_launch(void* const* d_in, const int* in_sizes, int n_in,
                              void* d_out, int out_size, void* d_ws, size_t ws_size,
                              hipStream_t stream) {
  (void)in_sizes; (void)n_in; (void)out_size; (void)ws_size;
  const float* preds = (const float*)d_in[0];  // [3,8,2,512,512] f32
  const float* cams  = (const float*)d_in[1];  // [8,1,512,512]  f32
  float* out = (float*)d_out;                  // scalar f32

  int* parent = (int*)d_ws;
  int* areas  = parent + (NIMG << LOG2HW);
  unsigned short* L16 = (unsigned short*)(areas + (NIMG << LOG2HW));
  unsigned int* rootPack = (unsigned int*)(L16 + ((size_t)NIMG << LOG2HW));
  int* rootF   = (int*)(rootPack + NIMG * 64 * RCAP);
  int* rootCnt = rootF + NIMG * 64 * RCAP;
  int* bL = rootCnt + NIMG * 64;
  int* bR = bL + NIMG * 64 * 64;
  int* bT = bR + NIMG * 64 * 64;
  int* bB = bT + NIMG * 64 * 64;
  int* maxa = bB + NIMG * 64 * 64;
  double* sums = (double*)(maxa + 16);         // 8-aligned (all prior sizes mult of 8B)
  int* counts  = (int*)(sums + 2);

  k_local  <<<Bsz * 64, 1024, 0, stream>>>(cams, parent, areas, L16, rootPack,
                                           rootCnt, bL, bR, bT, bB);
  k_border <<<NIMG * 7168 / 256, 256, 0, stream>>>(parent, bL, bR, bT, bB,
                                                   maxa, sums, counts);
  k_flatten<<<NIMG * 64, 256, 0, stream>>>(parent, areas, rootPack, rootF, rootCnt);
  k_max    <<<NIMG * 64, 256, 0, stream>>>(areas, rootF, rootCnt, maxa);
  k_keepce <<<Bsz * 64, 1024, 0, stream>>>(preds, L16, rootPack, rootF, rootCnt,
                                           maxa, sums, counts);
  k_final  <<<1, 64, 0, stream>>>(sums, counts, out);
}